// Round 1
// baseline (198.344 us; speedup 1.0000x reference)
//
#include <hip/hip_runtime.h>
#include <hip/hip_bf16.h>

#define B_ 8
#define N_ 4096
#define F_ 240
#define H_ 32
#define L_ 240
#define C_ 256   /* B_*H_ : merged batch*feature column dim */
#define KS 4     /* stage2 K-splits */

typedef __attribute__((ext_vector_type(8))) short bf16x8;
typedef __attribute__((ext_vector_type(4))) short bf16x4;
typedef __attribute__((ext_vector_type(4))) float f32x4;

__device__ __forceinline__ short f2bf(float f) {
    union { float f; unsigned u; } v; v.f = f;
    unsigned r = (v.u + 0x7FFFu + ((v.u >> 16) & 1u)) >> 16;
    return (short)r;
}

// ---------------- stage 1: HcT[c=b*32+h][m] = sum_f x[b,m,f]*W1[f,h] (bf16) ----
// D = A*B with A = W1^T (h x f), B = x (f-major per m col) -> D[h][m]
__global__ __launch_bounds__(256) void stage1(const float* __restrict__ x,
                                              const float* __restrict__ W1,
                                              short* __restrict__ HcT) {
    __shared__ short w1t[32][264];   // [h][f], padded, f 240..255 zeroed
    __shared__ short xt[64][264];    // [m][f]
    const int tid = threadIdx.x;
    const int b  = blockIdx.x >> 6;
    const int m0 = (blockIdx.x & 63) << 6;

    for (int idx = tid; idx < 240 * 32; idx += 256) {
        int f = idx >> 5, h = idx & 31;
        w1t[h][f] = f2bf(W1[idx]);
    }
    for (int idx = tid; idx < 32 * 16; idx += 256) {
        int h = idx >> 4, f = 240 + (idx & 15);
        w1t[h][f] = 0;
    }
    const float* xb = x + ((long)b * N_ + m0) * F_;
    for (int idx = tid; idx < 64 * 60; idx += 256) {
        int row = idx / 60, c4 = idx % 60;
        float4 v = *(const float4*)(xb + row * F_ + c4 * 4);
        bf16x4 s; s.x = f2bf(v.x); s.y = f2bf(v.y); s.z = f2bf(v.z); s.w = f2bf(v.w);
        *(bf16x4*)&xt[row][c4 * 4] = s;
    }
    for (int idx = tid; idx < 64 * 4; idx += 256) {
        int row = idx >> 2, f = 240 + (idx & 3) * 4;
        bf16x4 z = {0, 0, 0, 0};
        *(bf16x4*)&xt[row][f] = z;
    }
    __syncthreads();

    const int w = tid >> 6, lane = tid & 63, q = lane >> 4, r = lane & 15;
    f32x4 acc0 = {0,0,0,0}, acc1 = {0,0,0,0};
#pragma unroll
    for (int kk = 0; kk < 8; ++kk) {
        bf16x8 bfr = *(const bf16x8*)&xt[w * 16 + r][kk * 32 + q * 8];
        bf16x8 a0  = *(const bf16x8*)&w1t[r][kk * 32 + q * 8];
        bf16x8 a1  = *(const bf16x8*)&w1t[16 + r][kk * 32 + q * 8];
        acc0 = __builtin_amdgcn_mfma_f32_16x16x32_bf16(a0, bfr, acc0, 0, 0, 0);
        acc1 = __builtin_amdgcn_mfma_f32_16x16x32_bf16(a1, bfr, acc1, 0, 0, 0);
    }
    const int m = m0 + w * 16 + r;
#pragma unroll
    for (int reg = 0; reg < 4; ++reg) {
        int h0 = q * 4 + reg;
        HcT[(b * 32 + h0) * N_ + m]      = f2bf(acc0[reg]);
        HcT[(b * 32 + 16 + h0) * N_ + m] = f2bf(acc1[reg]);
    }
}

// ---------------- stage 2: P[ks][n][c] = sum_{k in chunk} a[n,k]*HcT[c][k] -----
template <bool ATOMIC>
__global__ __launch_bounds__(256) void stage2(const float* __restrict__ a,
                                              const short* __restrict__ HcT,
                                              float* __restrict__ P) {
    __shared__ short als[32][40];    // a tile  [m][k], bf16, padded row
    __shared__ short hls[256][40];   // Hc^T    [c][k], bf16, padded row
    const int tid = threadIdx.x;
    const int bm = blockIdx.x >> 2;          // 0..127 m-tiles of 32
    const int ks = blockIdx.x & 3;
    const int m0 = bm << 5;
    const int k0 = ks << 10;                 // 1024-k chunk

    const int w = tid >> 6, lane = tid & 63, q = lane >> 4, r = lane & 15;

    f32x4 acc[2][4];
#pragma unroll
    for (int i = 0; i < 2; ++i)
#pragma unroll
        for (int j = 0; j < 4; ++j) acc[i][j] = (f32x4){0, 0, 0, 0};

    const int arow = tid >> 3, acol = (tid & 7) * 4;

    for (int t = 0; t < 32; ++t) {
        const int k = k0 + t * 32;
        __syncthreads();
        {
            float4 v = *(const float4*)(a + (long)(m0 + arow) * N_ + k + acol);
            bf16x4 s; s.x = f2bf(v.x); s.y = f2bf(v.y); s.z = f2bf(v.z); s.w = f2bf(v.w);
            *(bf16x4*)&als[arow][acol] = s;
        }
#pragma unroll
        for (int i = 0; i < 4; ++i) {
            int idx = tid + i * 256;
            int c = idx >> 2, kb = idx & 3;
            bf16x8 v = *(const bf16x8*)(HcT + (long)c * N_ + k + kb * 8);
            *(bf16x8*)&hls[c][kb * 8] = v;
        }
        __syncthreads();
#pragma unroll
        for (int i = 0; i < 2; ++i) {
            bf16x8 af = *(const bf16x8*)&als[i * 16 + r][q * 8];
#pragma unroll
            for (int j = 0; j < 4; ++j) {
                bf16x8 bfr = *(const bf16x8*)&hls[w * 64 + j * 16 + r][q * 8];
                acc[i][j] = __builtin_amdgcn_mfma_f32_16x16x32_bf16(af, bfr, acc[i][j], 0, 0, 0);
            }
        }
    }
#pragma unroll
    for (int i = 0; i < 2; ++i)
#pragma unroll
        for (int j = 0; j < 4; ++j) {
            int c = w * 64 + j * 16 + r;
#pragma unroll
            for (int reg = 0; reg < 4; ++reg) {
                int m = m0 + i * 16 + q * 4 + reg;
                if (ATOMIC) atomicAdd(&P[(long)m * C_ + c], acc[i][j][reg]);
                else        P[((long)ks * N_ + m) * C_ + c] = acc[i][j][reg];
            }
        }
}

// ---------------- stage 3: out = relu(sum_ks P + b1) @ W2 + b2 -----------------
__global__ __launch_bounds__(256) void stage3(const float* __restrict__ P,
                                              const float* __restrict__ b1,
                                              const float* __restrict__ W2,
                                              const float* __restrict__ b2,
                                              float* __restrict__ out,
                                              int nks) {
    __shared__ float h2[64][32];
    const int tid = threadIdx.x;
    const int g0 = blockIdx.x * 64;          // first (b,n) row
    const int b  = g0 >> 12;
    const int n0 = g0 & 4095;

    for (int idx = tid; idx < 64 * 32; idx += 256) {
        int rr = idx >> 5, h = idx & 31;
        long base = (long)(n0 + rr) * C_ + b * 32 + h;
        float v = b1[h];
        for (int ks = 0; ks < nks; ++ks) v += P[(long)ks * (N_ * C_) + base];
        h2[rr][h] = v > 0.f ? v : 0.f;
    }
    __syncthreads();

    if (tid < 240) {
        const int l = tid;
        float w2r[32];
#pragma unroll
        for (int h = 0; h < 32; ++h) w2r[h] = W2[h * 240 + l];
        const float bias = b2[l];
        for (int rr = 0; rr < 64; ++rr) {
            const f32x4* hv = (const f32x4*)h2[rr];
            float acc = bias;
#pragma unroll
            for (int hh = 0; hh < 8; ++hh) {
                f32x4 v = hv[hh];
                acc += v[0] * w2r[hh * 4 + 0];
                acc += v[1] * w2r[hh * 4 + 1];
                acc += v[2] * w2r[hh * 4 + 2];
                acc += v[3] * w2r[hh * 4 + 3];
            }
            out[(long)(g0 + rr) * 240 + l] = acc;
        }
    }
}

extern "C" void kernel_launch(void* const* d_in, const int* in_sizes, int n_in,
                              void* d_out, int out_size, void* d_ws, size_t ws_size,
                              hipStream_t stream) {
    const float* x  = (const float*)d_in[0];
    const float* a  = (const float*)d_in[1];
    const float* W1 = (const float*)d_in[2];
    const float* b1 = (const float*)d_in[3];
    const float* W2 = (const float*)d_in[4];
    const float* b2 = (const float*)d_in[5];
    float* out = (float*)d_out;

    short* HcT = (short*)d_ws;                                   // 2 MB bf16
    float* P   = (float*)((char*)d_ws + (size_t)C_ * N_ * 2);    // partials
    const size_t need = (size_t)C_ * N_ * 2 + (size_t)KS * N_ * C_ * 4;

    stage1<<<512, 256, 0, stream>>>(x, W1, HcT);
    if (ws_size >= need) {
        stage2<false><<<512, 256, 0, stream>>>(a, HcT, P);
        stage3<<<512, 256, 0, stream>>>(P, b1, W2, b2, out, KS);
    } else {
        hipMemsetAsync(P, 0, (size_t)N_ * C_ * 4, stream);
        stage2<true><<<512, 256, 0, stream>>>(a, HcT, P);
        stage3<<<512, 256, 0, stream>>>(P, b1, W2, b2, out, 1);
    }
}

// Round 2
// 171.399 us; speedup vs baseline: 1.1572x; 1.1572x over previous
//
#include <hip/hip_runtime.h>
#include <hip/hip_bf16.h>

#define B_ 8
#define N_ 4096
#define F_ 240
#define H_ 32
#define L_ 240
#define C_ 256   /* B_*H_ merged column dim */
#define KS 8     /* stage2 K-splits */
#define MT 64    /* stage2 m-tile */

typedef __attribute__((ext_vector_type(8))) short bf16x8;
typedef __attribute__((ext_vector_type(4))) short bf16x4;
typedef __attribute__((ext_vector_type(4))) float f32x4;

__device__ __forceinline__ short f2bf(float f) {
    union { float f; unsigned u; } v; v.f = f;
    unsigned r = (v.u + 0x7FFFu + ((v.u >> 16) & 1u)) >> 16;
    return (short)r;
}

// HcF: Hc stored in MFMA B-fragment order.
// 16B unit u = ((kb*16 + ct)*2 + kp)*64 + q*16 + r holds
// Hc^T[c = ct*16 + r][k = kb*64 + kp*32 + q*8 + e], e = 0..7.
__device__ __forceinline__ long hcf_sidx(int c, int m) {
    return ((long)(((((m >> 6) * 16 + (c >> 4)) * 2 + ((m >> 5) & 1)) * 64)
                   + ((m >> 3) & 3) * 16 + (c & 15))) * 8 + (m & 7);
}

// ---------------- stage 1: Hc = x@W1 (bf16), written in B-frag order --------
__global__ __launch_bounds__(256) void stage1(const float* __restrict__ x,
                                              const float* __restrict__ W1,
                                              short* __restrict__ HcF) {
    __shared__ short w1t[32][264];
    __shared__ short xt[64][264];
    const int tid = threadIdx.x;
    const int b  = blockIdx.x >> 6;
    const int m0 = (blockIdx.x & 63) << 6;

    for (int idx = tid; idx < 240 * 32; idx += 256) {
        int f = idx >> 5, h = idx & 31;
        w1t[h][f] = f2bf(W1[idx]);
    }
    for (int idx = tid; idx < 32 * 16; idx += 256) {
        int h = idx >> 4, f = 240 + (idx & 15);
        w1t[h][f] = 0;
    }
    const float* xb = x + ((long)b * N_ + m0) * F_;
    for (int idx = tid; idx < 64 * 60; idx += 256) {
        int row = idx / 60, c4 = idx % 60;
        float4 v = *(const float4*)(xb + row * F_ + c4 * 4);
        bf16x4 s; s.x = f2bf(v.x); s.y = f2bf(v.y); s.z = f2bf(v.z); s.w = f2bf(v.w);
        *(bf16x4*)&xt[row][c4 * 4] = s;
    }
    for (int idx = tid; idx < 64 * 4; idx += 256) {
        int row = idx >> 2, f = 240 + (idx & 3) * 4;
        bf16x4 z = {0, 0, 0, 0};
        *(bf16x4*)&xt[row][f] = z;
    }
    __syncthreads();

    const int w = tid >> 6, lane = tid & 63, q = lane >> 4, r = lane & 15;
    f32x4 acc0 = {0,0,0,0}, acc1 = {0,0,0,0};
#pragma unroll
    for (int kk = 0; kk < 8; ++kk) {
        bf16x8 bfr = *(const bf16x8*)&xt[w * 16 + r][kk * 32 + q * 8];
        bf16x8 a0  = *(const bf16x8*)&w1t[r][kk * 32 + q * 8];
        bf16x8 a1  = *(const bf16x8*)&w1t[16 + r][kk * 32 + q * 8];
        acc0 = __builtin_amdgcn_mfma_f32_16x16x32_bf16(a0, bfr, acc0, 0, 0, 0);
        acc1 = __builtin_amdgcn_mfma_f32_16x16x32_bf16(a1, bfr, acc1, 0, 0, 0);
    }
    const int m = m0 + w * 16 + r;
#pragma unroll
    for (int reg = 0; reg < 4; ++reg) {
        int h0 = q * 4 + reg;
        HcF[hcf_sidx(b * 32 + h0, m)]      = f2bf(acc0[reg]);
        HcF[hcf_sidx(b * 32 + 16 + h0, m)] = f2bf(acc1[reg]);
    }
}

// ---------------- stage 2: P[ks][m][c] partial GEMM, M-tile 64, BK=64 --------
// A (fp32 a -> bf16) through double-buffered frag-ordered LDS (1 barrier/iter).
// B read directly global->register from HcF (L2-resident, lane-contiguous).
template <bool ATOMIC>
__global__ __launch_bounds__(256, 2) void stage2(const float* __restrict__ a,
                                                 const short* __restrict__ HcF,
                                                 float* __restrict__ P) {
    __shared__ short als[2][512 * 8];   // 2 bufs x 512 frags x 16B
    const int tid = threadIdx.x;
    const int bm = blockIdx.x >> 3;     // 0..63 m-tiles of 64
    const int ks = blockIdx.x & 7;
    const int m0 = bm * MT;
    const int kb0 = ks * 8;             // k-chunk = 8 blocks of 64

    const int w = tid >> 6, lane = tid & 63, q = lane >> 4, r = lane & 15;
    const bf16x8* __restrict__ Hv = (const bf16x8*)HcF;

    f32x4 acc[4][4];
#pragma unroll
    for (int i = 0; i < 4; ++i)
#pragma unroll
        for (int j = 0; j < 4; ++j) acc[i][j] = (f32x4){0, 0, 0, 0};

    // A staging: thread handles frags f = tid, tid+256.
    // frag f: i=f>>7, kp=(f>>6)&1, fq=(f>>4)&3, fr=f&15 ->
    //   a[m0 + i*16 + fr][kb*64 + kp*32 + fq*8 .. +8)
    float pre[16];
    const int f0i  = tid >> 7,        f1i  = (tid + 256) >> 7;
    const int f0kp = (tid >> 6) & 1,  f1kp = ((tid + 256) >> 6) & 1;
    const int f0q  = (tid >> 4) & 3,  f0r = tid & 15;

#define LOAD_A(kb)                                                             \
    {                                                                          \
        const float* s0 = a + (long)(m0 + f0i * 16 + f0r) * N_                 \
                            + (kb) * 64 + f0kp * 32 + f0q * 8;                 \
        const float* s1 = a + (long)(m0 + f1i * 16 + f0r) * N_                 \
                            + (kb) * 64 + f1kp * 32 + f0q * 8;                 \
        float4 v0 = *(const float4*)s0, v1 = *(const float4*)(s0 + 4);         \
        float4 v2 = *(const float4*)s1, v3 = *(const float4*)(s1 + 4);         \
        pre[0]=v0.x; pre[1]=v0.y; pre[2]=v0.z; pre[3]=v0.w;                    \
        pre[4]=v1.x; pre[5]=v1.y; pre[6]=v1.z; pre[7]=v1.w;                    \
        pre[8]=v2.x; pre[9]=v2.y; pre[10]=v2.z; pre[11]=v2.w;                  \
        pre[12]=v3.x; pre[13]=v3.y; pre[14]=v3.z; pre[15]=v3.w;                \
    }
#define STORE_A(buf)                                                           \
    {                                                                          \
        bf16x8 s0, s1;                                                         \
        _Pragma("unroll") for (int e = 0; e < 8; ++e) {                        \
            s0[e] = f2bf(pre[e]); s1[e] = f2bf(pre[8 + e]);                    \
        }                                                                      \
        *(bf16x8*)&als[buf][tid * 8]         = s0;                             \
        *(bf16x8*)&als[buf][(tid + 256) * 8] = s1;                             \
    }

    LOAD_A(kb0);
    STORE_A(0);

    bf16x8 bcur[8];
#pragma unroll
    for (int kp = 0; kp < 2; ++kp)
#pragma unroll
        for (int j = 0; j < 4; ++j)
            bcur[kp * 4 + j] = Hv[(long)((kb0 * 16 + w * 4 + j) * 2 + kp) * 64 + lane];

    __syncthreads();

    for (int t = 0; t < 8; ++t) {
        const int cur = t & 1;
        bf16x8 bnxt[8];
        if (t < 7) {
            LOAD_A(kb0 + t + 1);
#pragma unroll
            for (int kp = 0; kp < 2; ++kp)
#pragma unroll
                for (int j = 0; j < 4; ++j)
                    bnxt[kp * 4 + j] =
                        Hv[(long)(((kb0 + t + 1) * 16 + w * 4 + j) * 2 + kp) * 64 + lane];
        }
#pragma unroll
        for (int kp = 0; kp < 2; ++kp)
#pragma unroll
            for (int i = 0; i < 4; ++i) {
                bf16x8 af = *(const bf16x8*)&als[cur][((i * 2 + kp) * 64 + lane) * 8];
#pragma unroll
                for (int j = 0; j < 4; ++j)
                    acc[i][j] = __builtin_amdgcn_mfma_f32_16x16x32_bf16(
                        af, bcur[kp * 4 + j], acc[i][j], 0, 0, 0);
            }
        if (t < 7) {
            STORE_A(!cur);
#pragma unroll
            for (int u = 0; u < 8; ++u) bcur[u] = bnxt[u];
        }
        __syncthreads();
    }

#pragma unroll
    for (int i = 0; i < 4; ++i)
#pragma unroll
        for (int j = 0; j < 4; ++j) {
            const int c = w * 64 + j * 16 + r;
#pragma unroll
            for (int reg = 0; reg < 4; ++reg) {
                const int m = m0 + i * 16 + q * 4 + reg;
                if (ATOMIC) atomicAdd(&P[(long)m * C_ + c], acc[i][j][reg]);
                else        P[((long)ks * N_ + m) * C_ + c] = acc[i][j][reg];
            }
        }
#undef LOAD_A
#undef STORE_A
}

// ---------------- stage 3: out = relu(sum_ks P + b1) @ W2 + b2 ---------------
__global__ __launch_bounds__(256) void stage3(const float* __restrict__ P,
                                              const float* __restrict__ b1,
                                              const float* __restrict__ W2,
                                              const float* __restrict__ b2,
                                              float* __restrict__ out,
                                              int nks) {
    __shared__ float h2[32][36];
    const int tid = threadIdx.x;
    const int g0 = blockIdx.x * 32;      // 32 (b,n) rows per block
    const int b  = g0 >> 12;
    const int n0 = g0 & 4095;

    {
        const int rr = tid >> 3, c4 = tid & 7;
        const float* base = P + (long)(n0 + rr) * C_ + b * 32 + c4 * 4;
        f32x4 s = *(const f32x4*)base;
        for (int ks = 1; ks < nks; ++ks)
            s += *(const f32x4*)(base + (long)ks * (N_ * C_));
        s += *(const f32x4*)(b1 + c4 * 4);
        f32x4 z;
#pragma unroll
        for (int e = 0; e < 4; ++e) z[e] = s[e] > 0.f ? s[e] : 0.f;
        *(f32x4*)&h2[rr][c4 * 4] = z;
    }
    __syncthreads();

    if (tid < 240) {
        const int l = tid;
        float w2r[32];
#pragma unroll
        for (int h = 0; h < 32; ++h) w2r[h] = W2[h * 240 + l];
        const float bias = b2[l];
        for (int rr = 0; rr < 32; ++rr) {
            const f32x4* hv = (const f32x4*)h2[rr];
            float acc = bias;
#pragma unroll
            for (int hh = 0; hh < 8; ++hh) {
                f32x4 v = hv[hh];
                acc += v[0] * w2r[hh * 4 + 0];
                acc += v[1] * w2r[hh * 4 + 1];
                acc += v[2] * w2r[hh * 4 + 2];
                acc += v[3] * w2r[hh * 4 + 3];
            }
            out[(long)(g0 + rr) * 240 + l] = acc;
        }
    }
}

extern "C" void kernel_launch(void* const* d_in, const int* in_sizes, int n_in,
                              void* d_out, int out_size, void* d_ws, size_t ws_size,
                              hipStream_t stream) {
    const float* x  = (const float*)d_in[0];
    const float* a  = (const float*)d_in[1];
    const float* W1 = (const float*)d_in[2];
    const float* b1 = (const float*)d_in[3];
    const float* W2 = (const float*)d_in[4];
    const float* b2 = (const float*)d_in[5];
    float* out = (float*)d_out;

    short* HcF = (short*)d_ws;                                   // 2 MB bf16 frag-order
    float* P   = (float*)((char*)d_ws + (size_t)C_ * N_ * 2);
    const size_t need = (size_t)C_ * N_ * 2 + (size_t)KS * N_ * C_ * 4;

    stage1<<<512, 256, 0, stream>>>(x, W1, HcF);
    if (ws_size >= need) {
        stage2<false><<<512, 256, 0, stream>>>(a, HcF, P);
        stage3<<<1024, 256, 0, stream>>>(P, b1, W2, b2, out, KS);
    } else {
        hipMemsetAsync(P, 0, (size_t)N_ * C_ * 4, stream);
        stage2<true><<<512, 256, 0, stream>>>(a, HcF, P);
        stage3<<<1024, 256, 0, stream>>>(P, b1, W2, b2, out, 1);
    }
}

// Round 3
// 170.828 us; speedup vs baseline: 1.1611x; 1.0033x over previous
//
#include <hip/hip_runtime.h>
#include <hip/hip_bf16.h>

#define B_ 8
#define N_ 4096
#define F_ 240
#define H_ 32
#define L_ 240
#define C_ 256   /* B_*H_ merged column dim */
#define KS 8     /* stage2 K-splits */

typedef __attribute__((ext_vector_type(8))) short bf16x8;
typedef __attribute__((ext_vector_type(4))) short bf16x4;
typedef __attribute__((ext_vector_type(4))) float f32x4;

__device__ __forceinline__ short f2bf(float f) {
    union { float f; unsigned u; } v; v.f = f;
    unsigned r = (v.u + 0x7FFFu + ((v.u >> 16) & 1u)) >> 16;
    return (short)r;
}
__device__ __forceinline__ float bf2f(short s) {
    union { unsigned u; float f; } v;
    v.u = ((unsigned)(unsigned short)s) << 16;
    return v.f;
}

// HcF: Hc stored in MFMA B-fragment order.
// 16B unit u = ((kb*16 + ct)*2 + kp)*64 + q*16 + r holds
// Hc^T[c = ct*16 + r][k = kb*64 + kp*32 + q*8 + e], e = 0..7.
__device__ __forceinline__ long hcf_sidx(int c, int m) {
    return ((long)(((((m >> 6) * 16 + (c >> 4)) * 2 + ((m >> 5) & 1)) * 64)
                   + ((m >> 3) & 3) * 16 + (c & 15))) * 8 + (m & 7);
}

// ---------------- stage 1: Hc = x@W1 (bf16), written in B-frag order --------
__global__ __launch_bounds__(256) void stage1(const float* __restrict__ x,
                                              const float* __restrict__ W1,
                                              short* __restrict__ HcF) {
    __shared__ short w1t[32][264];
    __shared__ short xt[64][264];
    const int tid = threadIdx.x;
    const int b  = blockIdx.x >> 6;
    const int m0 = (blockIdx.x & 63) << 6;

    for (int idx = tid; idx < 240 * 32; idx += 256) {
        int f = idx >> 5, h = idx & 31;
        w1t[h][f] = f2bf(W1[idx]);
    }
    for (int idx = tid; idx < 32 * 16; idx += 256) {
        int h = idx >> 4, f = 240 + (idx & 15);
        w1t[h][f] = 0;
    }
    const float* xb = x + ((long)b * N_ + m0) * F_;
    for (int idx = tid; idx < 64 * 60; idx += 256) {
        int row = idx / 60, c4 = idx % 60;
        float4 v = *(const float4*)(xb + row * F_ + c4 * 4);
        bf16x4 s; s.x = f2bf(v.x); s.y = f2bf(v.y); s.z = f2bf(v.z); s.w = f2bf(v.w);
        *(bf16x4*)&xt[row][c4 * 4] = s;
    }
    for (int idx = tid; idx < 64 * 4; idx += 256) {
        int row = idx >> 2, f = 240 + (idx & 3) * 4;
        bf16x4 z = {0, 0, 0, 0};
        *(bf16x4*)&xt[row][f] = z;
    }
    __syncthreads();

    const int w = tid >> 6, lane = tid & 63, q = lane >> 4, r = lane & 15;
    f32x4 acc0 = {0,0,0,0}, acc1 = {0,0,0,0};
#pragma unroll
    for (int kk = 0; kk < 8; ++kk) {
        bf16x8 bfr = *(const bf16x8*)&xt[w * 16 + r][kk * 32 + q * 8];
        bf16x8 a0  = *(const bf16x8*)&w1t[r][kk * 32 + q * 8];
        bf16x8 a1  = *(const bf16x8*)&w1t[16 + r][kk * 32 + q * 8];
        acc0 = __builtin_amdgcn_mfma_f32_16x16x32_bf16(a0, bfr, acc0, 0, 0, 0);
        acc1 = __builtin_amdgcn_mfma_f32_16x16x32_bf16(a1, bfr, acc1, 0, 0, 0);
    }
    const int m = m0 + w * 16 + r;
#pragma unroll
    for (int reg = 0; reg < 4; ++reg) {
        int h0 = q * 4 + reg;
        HcF[hcf_sidx(b * 32 + h0, m)]      = f2bf(acc0[reg]);
        HcF[hcf_sidx(b * 32 + 16 + h0, m)] = f2bf(acc1[reg]);
    }
}

// ---------------- stage 2: P[ks][m][c] partial GEMM, M-tile 32, BK=64 --------
// A (fp32 a -> bf16) through double-buffered frag-ordered LDS (1 barrier/iter).
// B read directly global->register from HcF (L2/L3-resident, lane-contiguous).
// P stored as bf16 (halves round-trip traffic; adds ~0.2 absmax vs 2.9 thr).
template <bool ATOMIC>
__global__ __launch_bounds__(256, 3) void stage2(const float* __restrict__ a,
                                                 const short* __restrict__ HcF,
                                                 void* __restrict__ Pv) {
    __shared__ short als[2][256 * 8];   // 2 bufs x 256 frags x 16B = 8 KB
    const int tid = threadIdx.x;
    const int bm = blockIdx.x >> 3;     // 0..127 m-tiles of 32
    const int ks = blockIdx.x & 7;
    const int m0 = bm * 32;
    const int kb0 = ks * 8;             // k-chunk = 8 blocks of 64

    const int w = tid >> 6, lane = tid & 63, q = lane >> 4, r = lane & 15;
    const bf16x8* __restrict__ Hv = (const bf16x8*)HcF;

    f32x4 acc[2][4];
#pragma unroll
    for (int i = 0; i < 2; ++i)
#pragma unroll
        for (int j = 0; j < 4; ++j) acc[i][j] = (f32x4){0, 0, 0, 0};

    // A staging: one 16B frag per thread.
    // frag f = tid: i=f>>7, kp=(f>>6)&1, q=(f>>4)&3, r=f&15 ->
    //   a[m0 + i*16 + r][kb*64 + kp*32 + q*8 .. +8)
    float pre[8];
    const int fi = tid >> 7, fkp = (tid >> 6) & 1, fq = (tid >> 4) & 3, fr = tid & 15;

#define LOAD_A(kb)                                                             \
    {                                                                          \
        const float* s = a + (long)(m0 + fi * 16 + fr) * N_                    \
                           + (kb) * 64 + fkp * 32 + fq * 8;                    \
        float4 v0 = *(const float4*)s, v1 = *(const float4*)(s + 4);           \
        pre[0]=v0.x; pre[1]=v0.y; pre[2]=v0.z; pre[3]=v0.w;                    \
        pre[4]=v1.x; pre[5]=v1.y; pre[6]=v1.z; pre[7]=v1.w;                    \
    }
#define STORE_A(buf)                                                           \
    {                                                                          \
        bf16x8 s0;                                                             \
        _Pragma("unroll") for (int e = 0; e < 8; ++e) s0[e] = f2bf(pre[e]);    \
        *(bf16x8*)&als[buf][tid * 8] = s0;                                     \
    }

    LOAD_A(kb0);
    STORE_A(0);

    bf16x8 bcur[8];
#pragma unroll
    for (int kp = 0; kp < 2; ++kp)
#pragma unroll
        for (int j = 0; j < 4; ++j)
            bcur[kp * 4 + j] = Hv[(long)((kb0 * 16 + w * 4 + j) * 2 + kp) * 64 + lane];

    __syncthreads();

    for (int t = 0; t < 8; ++t) {
        const int cur = t & 1;
        bf16x8 bnxt[8];
        if (t < 7) {
            LOAD_A(kb0 + t + 1);
#pragma unroll
            for (int kp = 0; kp < 2; ++kp)
#pragma unroll
                for (int j = 0; j < 4; ++j)
                    bnxt[kp * 4 + j] =
                        Hv[(long)(((kb0 + t + 1) * 16 + w * 4 + j) * 2 + kp) * 64 + lane];
        }
#pragma unroll
        for (int kp = 0; kp < 2; ++kp)
#pragma unroll
            for (int i = 0; i < 2; ++i) {
                bf16x8 af = *(const bf16x8*)&als[cur][((i * 2 + kp) * 64 + lane) * 8];
#pragma unroll
                for (int j = 0; j < 4; ++j)
                    acc[i][j] = __builtin_amdgcn_mfma_f32_16x16x32_bf16(
                        af, bcur[kp * 4 + j], acc[i][j], 0, 0, 0);
            }
        if (t < 7) {
            STORE_A(!cur);
#pragma unroll
            for (int u = 0; u < 8; ++u) bcur[u] = bnxt[u];
        }
        __syncthreads();
    }

    if (!ATOMIC) {
        short* __restrict__ P = (short*)Pv;
#pragma unroll
        for (int i = 0; i < 2; ++i)
#pragma unroll
            for (int j = 0; j < 4; ++j) {
                const int c = w * 64 + j * 16 + r;
#pragma unroll
                for (int reg = 0; reg < 4; ++reg) {
                    const int m = m0 + i * 16 + q * 4 + reg;
                    P[((long)ks * N_ + m) * C_ + c] = f2bf(acc[i][j][reg]);
                }
            }
    } else {
        float* __restrict__ P = (float*)Pv;
#pragma unroll
        for (int i = 0; i < 2; ++i)
#pragma unroll
            for (int j = 0; j < 4; ++j) {
                const int c = w * 64 + j * 16 + r;
#pragma unroll
                for (int reg = 0; reg < 4; ++reg) {
                    const int m = m0 + i * 16 + q * 4 + reg;
                    atomicAdd(&P[(long)m * C_ + c], acc[i][j][reg]);
                }
            }
    }
#undef LOAD_A
#undef STORE_A
}

// ---------------- stage 3: out = relu(sum_ks P + b1) @ W2 + b2 ---------------
template <bool BF16P>
__global__ __launch_bounds__(256) void stage3(const void* __restrict__ Pv,
                                              const float* __restrict__ b1,
                                              const float* __restrict__ W2,
                                              const float* __restrict__ b2,
                                              float* __restrict__ out,
                                              int nks) {
    __shared__ float h2[32][36];
    const int tid = threadIdx.x;
    const int g0 = blockIdx.x * 32;      // 32 (b,n) rows per block
    const int b  = g0 >> 12;
    const int n0 = g0 & 4095;

    {
        const int rr = tid >> 3, cg = tid & 7;   // 8 threads x 4 h per row
        float s[4];
        float4 bb = *(const float4*)(b1 + cg * 4);
        s[0] = bb.x; s[1] = bb.y; s[2] = bb.z; s[3] = bb.w;
        if (BF16P) {
            const short* base = (const short*)Pv + (long)(n0 + rr) * C_ + b * 32 + cg * 4;
            for (int ks = 0; ks < nks; ++ks) {
                bf16x4 v = *(const bf16x4*)(base + (long)ks * (N_ * C_));
#pragma unroll
                for (int e = 0; e < 4; ++e) s[e] += bf2f(v[e]);
            }
        } else {
            const float* base = (const float*)Pv + (long)(n0 + rr) * C_ + b * 32 + cg * 4;
            for (int ks = 0; ks < nks; ++ks) {
                f32x4 v = *(const f32x4*)(base + (long)ks * (N_ * C_));
#pragma unroll
                for (int e = 0; e < 4; ++e) s[e] += v[e];
            }
        }
#pragma unroll
        for (int e = 0; e < 4; ++e) h2[rr][cg * 4 + e] = s[e] > 0.f ? s[e] : 0.f;
    }
    __syncthreads();

    if (tid < 240) {
        const int l = tid;
        float w2r[32];
#pragma unroll
        for (int h = 0; h < 32; ++h) w2r[h] = W2[h * 240 + l];
        const float bias = b2[l];
        for (int rr = 0; rr < 32; ++rr) {
            const f32x4* hv = (const f32x4*)h2[rr];
            float acc = bias;
#pragma unroll
            for (int hh = 0; hh < 8; ++hh) {
                f32x4 v = hv[hh];
                acc += v[0] * w2r[hh * 4 + 0];
                acc += v[1] * w2r[hh * 4 + 1];
                acc += v[2] * w2r[hh * 4 + 2];
                acc += v[3] * w2r[hh * 4 + 3];
            }
            out[(long)(g0 + rr) * 240 + l] = acc;
        }
    }
}

extern "C" void kernel_launch(void* const* d_in, const int* in_sizes, int n_in,
                              void* d_out, int out_size, void* d_ws, size_t ws_size,
                              hipStream_t stream) {
    const float* x  = (const float*)d_in[0];
    const float* a  = (const float*)d_in[1];
    const float* W1 = (const float*)d_in[2];
    const float* b1 = (const float*)d_in[3];
    const float* W2 = (const float*)d_in[4];
    const float* b2 = (const float*)d_in[5];
    float* out = (float*)d_out;

    short* HcF = (short*)d_ws;                                   // 2 MB bf16 frag-order
    void*  P   = (void*)((char*)d_ws + (size_t)C_ * N_ * 2);
    const size_t need_bf16 = (size_t)C_ * N_ * 2 + (size_t)KS * N_ * C_ * 2;
    const size_t need_f32  = (size_t)C_ * N_ * 2 + (size_t)N_ * C_ * 4;

    stage1<<<512, 256, 0, stream>>>(x, W1, HcF);
    if (ws_size >= need_bf16) {
        stage2<false><<<1024, 256, 0, stream>>>(a, HcF, P);
        stage3<true><<<1024, 256, 0, stream>>>(P, b1, W2, b2, out, KS);
    } else if (ws_size >= need_f32) {
        hipMemsetAsync(P, 0, (size_t)N_ * C_ * 4, stream);
        stage2<true><<<1024, 256, 0, stream>>>(a, HcF, P);
        stage3<false><<<1024, 256, 0, stream>>>(P, b1, W2, b2, out, 1);
    }
}

// Round 4
// 161.977 us; speedup vs baseline: 1.2245x; 1.0546x over previous
//
#include <hip/hip_runtime.h>
#include <hip/hip_bf16.h>

#define B_ 8
#define N_ 4096
#define F_ 240
#define H_ 32
#define L_ 240
#define C_ 256   /* B_*H_ merged column dim */
#define KS 8     /* stage2 K-splits */

typedef __attribute__((ext_vector_type(8))) short bf16x8;
typedef __attribute__((ext_vector_type(4))) short bf16x4;
typedef __attribute__((ext_vector_type(4))) float f32x4;

__device__ __forceinline__ short f2bf(float f) {
    union { float f; unsigned u; } v; v.f = f;
    unsigned r = (v.u + 0x7FFFu + ((v.u >> 16) & 1u)) >> 16;
    return (short)r;
}
__device__ __forceinline__ float bf2f(short s) {
    union { unsigned u; float f; } v;
    v.u = ((unsigned)(unsigned short)s) << 16;
    return v.f;
}

// HcF: Hc stored in MFMA B-fragment order.
// 16B unit u = ((kb*16 + ct)*2 + kp)*64 + q*16 + r holds
// Hc^T[c = ct*16 + r][k = kb*64 + kp*32 + q*8 + e], e = 0..7.
__device__ __forceinline__ long hcf_sidx(int c, int m) {
    return ((long)(((((m >> 6) * 16 + (c >> 4)) * 2 + ((m >> 5) & 1)) * 64)
                   + ((m >> 3) & 3) * 16 + (c & 15))) * 8 + (m & 7);
}

// ---------------- stage 1: Hc = x@W1 (bf16), written in B-frag order --------
__global__ __launch_bounds__(256) void stage1(const float* __restrict__ x,
                                              const float* __restrict__ W1,
                                              short* __restrict__ HcF) {
    __shared__ short w1t[32][264];
    __shared__ short xt[64][264];
    const int tid = threadIdx.x;
    const int b  = blockIdx.x >> 6;
    const int m0 = (blockIdx.x & 63) << 6;

    for (int idx = tid; idx < 240 * 32; idx += 256) {
        int f = idx >> 5, h = idx & 31;
        w1t[h][f] = f2bf(W1[idx]);
    }
    for (int idx = tid; idx < 32 * 16; idx += 256) {
        int h = idx >> 4, f = 240 + (idx & 15);
        w1t[h][f] = 0;
    }
    const float* xb = x + ((long)b * N_ + m0) * F_;
    for (int idx = tid; idx < 64 * 60; idx += 256) {
        int row = idx / 60, c4 = idx % 60;
        float4 v = *(const float4*)(xb + row * F_ + c4 * 4);
        bf16x4 s; s.x = f2bf(v.x); s.y = f2bf(v.y); s.z = f2bf(v.z); s.w = f2bf(v.w);
        *(bf16x4*)&xt[row][c4 * 4] = s;
    }
    for (int idx = tid; idx < 64 * 4; idx += 256) {
        int row = idx >> 2, f = 240 + (idx & 3) * 4;
        bf16x4 z = {0, 0, 0, 0};
        *(bf16x4*)&xt[row][f] = z;
    }
    __syncthreads();

    const int w = tid >> 6, lane = tid & 63, q = lane >> 4, r = lane & 15;
    f32x4 acc0 = {0,0,0,0}, acc1 = {0,0,0,0};
#pragma unroll
    for (int kk = 0; kk < 8; ++kk) {
        bf16x8 bfr = *(const bf16x8*)&xt[w * 16 + r][kk * 32 + q * 8];
        bf16x8 a0  = *(const bf16x8*)&w1t[r][kk * 32 + q * 8];
        bf16x8 a1  = *(const bf16x8*)&w1t[16 + r][kk * 32 + q * 8];
        acc0 = __builtin_amdgcn_mfma_f32_16x16x32_bf16(a0, bfr, acc0, 0, 0, 0);
        acc1 = __builtin_amdgcn_mfma_f32_16x16x32_bf16(a1, bfr, acc1, 0, 0, 0);
    }
    const int m = m0 + w * 16 + r;
#pragma unroll
    for (int reg = 0; reg < 4; ++reg) {
        int h0 = q * 4 + reg;
        HcF[hcf_sidx(b * 32 + h0, m)]      = f2bf(acc0[reg]);
        HcF[hcf_sidx(b * 32 + 16 + h0, m)] = f2bf(acc1[reg]);
    }
}

// ---------------- stage 2: frag-linear bf16 partials, MT=64, BK=64, KS=8 -----
// A (fp32 a -> bf16) via double-buffered frag-ordered LDS, DEPTH-2 register
// prefetch on the HBM stream. B direct global->reg from HcF (L2-resident,
// ks == XCD so each XCD's L2 caches its 262 KB B-chunk).
// P layout: frag-block F = ((ks*64+bm)*4+w)*16 + i*4+j ; shorts F*256+lane*4.
__global__ __launch_bounds__(256, 2) void stage2(const float* __restrict__ a,
                                                 const short* __restrict__ HcF,
                                                 short* __restrict__ P) {
    __shared__ short als[2][512 * 8];   // 16 KB: 512 frags x 16B, double-buffered
    const int tid = threadIdx.x;
    const int bm = blockIdx.x >> 3;     // 0..63 m-tiles of 64
    const int ks = blockIdx.x & 7;      // == XCD id for L2 locality on B
    const int m0 = bm << 6;
    const int kb0 = ks << 3;            // 8 k-blocks of 64

    const int w = tid >> 6, lane = tid & 63, q = lane >> 4, r = lane & 15;
    const bf16x8* __restrict__ Hv = (const bf16x8*)HcF;

    f32x4 acc[4][4];
#pragma unroll
    for (int i = 0; i < 4; ++i)
#pragma unroll
        for (int j = 0; j < 4; ++j) acc[i][j] = (f32x4){0, 0, 0, 0};

    // A frag f: i=f>>7, kp=(f>>6)&1, q=(f>>4)&3, r=f&15. Thread owns f=tid, tid+256.
    const int fi = tid >> 7, fkp = (tid >> 6) & 1, fq = (tid >> 4) & 3, fr = tid & 15;
    const float* aB0 = a + (long)(m0 + fi * 16 + fr) * N_ + (kb0 << 6) + fkp * 32 + fq * 8;
    const float* aB1 = aB0 + 32 * N_;
    float pre[2][16];

#define LOAD_A(bk, t)                                                          \
    {                                                                          \
        const float* s0 = aB0 + (t) * 64;                                      \
        const float* s1 = aB1 + (t) * 64;                                      \
        float4 v0 = *(const float4*)s0, v1 = *(const float4*)(s0 + 4);         \
        float4 v2 = *(const float4*)s1, v3 = *(const float4*)(s1 + 4);         \
        pre[bk][0]=v0.x;  pre[bk][1]=v0.y;  pre[bk][2]=v0.z;  pre[bk][3]=v0.w; \
        pre[bk][4]=v1.x;  pre[bk][5]=v1.y;  pre[bk][6]=v1.z;  pre[bk][7]=v1.w; \
        pre[bk][8]=v2.x;  pre[bk][9]=v2.y;  pre[bk][10]=v2.z; pre[bk][11]=v2.w;\
        pre[bk][12]=v3.x; pre[bk][13]=v3.y; pre[bk][14]=v3.z; pre[bk][15]=v3.w;\
    }
#define STORE_A(bk, buf)                                                       \
    {                                                                          \
        bf16x8 s0, s1;                                                         \
        _Pragma("unroll") for (int e = 0; e < 8; ++e) {                        \
            s0[e] = f2bf(pre[bk][e]); s1[e] = f2bf(pre[bk][8 + e]);            \
        }                                                                      \
        *(bf16x8*)&als[buf][tid * 8]         = s0;                             \
        *(bf16x8*)&als[buf][(tid + 256) * 8] = s1;                             \
    }

    bf16x8 bcur[8], bnxt[8];
    LOAD_A(0, 0);
    LOAD_A(1, 1);
#pragma unroll
    for (int kp = 0; kp < 2; ++kp)
#pragma unroll
        for (int j = 0; j < 4; ++j)
            bcur[kp * 4 + j] = Hv[(long)((kb0 * 16 + w * 4 + j) * 2 + kp) * 64 + lane];
    STORE_A(0, 0);
    __syncthreads();

#pragma unroll
    for (int t = 0; t < 8; ++t) {
        const int cur = t & 1;
        if (t < 6) LOAD_A(cur, t + 2);          // bank[cur] freed last iter
        if (t < 7) {
#pragma unroll
            for (int kp = 0; kp < 2; ++kp)
#pragma unroll
                for (int j = 0; j < 4; ++j)
                    bnxt[kp * 4 + j] =
                        Hv[(long)(((kb0 + t + 1) * 16 + w * 4 + j) * 2 + kp) * 64 + lane];
        }
#pragma unroll
        for (int kp = 0; kp < 2; ++kp)
#pragma unroll
            for (int i = 0; i < 4; ++i) {
                bf16x8 af = *(const bf16x8*)&als[cur][(i * 128 + kp * 64 + lane) * 8];
#pragma unroll
                for (int j = 0; j < 4; ++j)
                    acc[i][j] = __builtin_amdgcn_mfma_f32_16x16x32_bf16(
                        af, bcur[kp * 4 + j], acc[i][j], 0, 0, 0);
            }
        if (t < 7) {
            STORE_A(!cur, !cur);                // A(t+1): regs -> LDS
#pragma unroll
            for (int u = 0; u < 8; ++u) bcur[u] = bnxt[u];
        }
        __syncthreads();
    }

    // coalesced 8B frag-linear stores
#pragma unroll
    for (int i = 0; i < 4; ++i)
#pragma unroll
        for (int j = 0; j < 4; ++j) {
            bf16x4 v;
#pragma unroll
            for (int reg = 0; reg < 4; ++reg) v[reg] = f2bf(acc[i][j][reg]);
            const long F = (((long)ks * 64 + bm) * 4 + w) * 16 + i * 4 + j;
            *(bf16x4*)&P[F * 256 + lane * 4] = v;
        }
#undef LOAD_A
#undef STORE_A
}

// ---- fallback stage2: fp32 atomics into P[m][c] (if ws too small) ----------
__global__ __launch_bounds__(256, 2) void stage2_fb(const float* __restrict__ a,
                                                    const short* __restrict__ HcF,
                                                    float* __restrict__ P) {
    __shared__ short als[512 * 8];
    const int tid = threadIdx.x;
    const int bm = blockIdx.x >> 3, ks = blockIdx.x & 7;
    const int m0 = bm << 6, kb0 = ks << 3;
    const int w = tid >> 6, lane = tid & 63, q = lane >> 4, r = lane & 15;
    const bf16x8* __restrict__ Hv = (const bf16x8*)HcF;
    f32x4 acc[4][4];
#pragma unroll
    for (int i = 0; i < 4; ++i)
#pragma unroll
        for (int j = 0; j < 4; ++j) acc[i][j] = (f32x4){0, 0, 0, 0};
    const int fi = tid >> 7, fkp = (tid >> 6) & 1, fq = (tid >> 4) & 3, fr = tid & 15;
    for (int t = 0; t < 8; ++t) {
        __syncthreads();
        for (int u = 0; u < 2; ++u) {
            const float* s = a + (long)(m0 + (fi + 2 * u) * 16 + fr) * N_
                               + ((kb0 + t) << 6) + fkp * 32 + fq * 8;
            bf16x8 sv;
            for (int e = 0; e < 8; ++e) sv[e] = f2bf(s[e]);
            *(bf16x8*)&als[(tid + u * 256) * 8] = sv;
        }
        __syncthreads();
#pragma unroll
        for (int kp = 0; kp < 2; ++kp)
#pragma unroll
            for (int i = 0; i < 4; ++i) {
                bf16x8 af = *(const bf16x8*)&als[(i * 128 + kp * 64 + lane) * 8];
#pragma unroll
                for (int j = 0; j < 4; ++j) {
                    bf16x8 bfr = Hv[(long)(((kb0 + t) * 16 + w * 4 + j) * 2 + kp) * 64 + lane];
                    acc[i][j] = __builtin_amdgcn_mfma_f32_16x16x32_bf16(af, bfr, acc[i][j], 0, 0, 0);
                }
            }
    }
#pragma unroll
    for (int i = 0; i < 4; ++i)
#pragma unroll
        for (int j = 0; j < 4; ++j) {
            const int c = w * 64 + j * 16 + r;
#pragma unroll
            for (int reg = 0; reg < 4; ++reg)
                atomicAdd(&P[(long)(m0 + i * 16 + q * 4 + reg) * C_ + c], acc[i][j][reg]);
        }
}

// ---------------- stage 3: reduce ks + bias + relu + (h @ W2 + b2) via MFMA --
// block = (bm, i) -> 16 n-rows; 512 threads. Wave w2 owns batch b = w2.
__global__ __launch_bounds__(512) void stage3(const short* __restrict__ P,
                                              const float* __restrict__ b1,
                                              const float* __restrict__ W2,
                                              const float* __restrict__ b2,
                                              float* __restrict__ out) {
    __shared__ short h2A[8][16][48];   // [b][row][h], padded to 48 (16B-aligned rows)
    __shared__ short W2T[240][56];     // [l][h], padded to 56
    __shared__ float b2L[240];
    const int tid = threadIdx.x;
    const int bm = blockIdx.x >> 2, i = blockIdx.x & 3;
    const int n0 = (bm << 6) + (i << 4);
    const int w2 = tid >> 6, lane = tid & 63, q = lane >> 4, r = lane & 15;
    const int w = w2 >> 1, jp = w2 & 1;

    for (int idx = tid; idx < 240 * 32; idx += 512) {
        int h = idx / 240, l = idx - h * 240;
        W2T[l][h] = f2bf(W2[idx]);
    }
    if (tid < 240) b2L[tid] = b2[tid];

#pragma unroll
    for (int jj = 0; jj < 2; ++jj) {
        const int j = jp * 2 + jj;
        const int c = (w << 6) + (j << 4) + r;
        const float bb = b1[c & 31];
        float s[4] = {bb, bb, bb, bb};
        const long F0 = ((long)bm * 4 + w) * 16 + i * 4 + j;
#pragma unroll
        for (int ks = 0; ks < 8; ++ks) {
            bf16x4 v = *(const bf16x4*)&P[(F0 + (long)ks * 4096) * 256 + lane * 4];
#pragma unroll
            for (int e = 0; e < 4; ++e) s[e] += bf2f(v[e]);
        }
#pragma unroll
        for (int e = 0; e < 4; ++e) {
            float z = s[e] > 0.f ? s[e] : 0.f;
            h2A[w2][q * 4 + e][(jj << 4) + r] = f2bf(z);
        }
    }
    __syncthreads();

    bf16x8 af = *(const bf16x8*)&h2A[w2][r][q * 8];
    float* outB = out + ((long)w2 * N_ + n0) * 240;
#pragma unroll
    for (int lt = 0; lt < 15; ++lt) {
        bf16x8 bf = *(const bf16x8*)&W2T[lt * 16 + r][q * 8];
        f32x4 acc = {0, 0, 0, 0};
        acc = __builtin_amdgcn_mfma_f32_16x16x32_bf16(af, bf, acc, 0, 0, 0);
        const float bias = b2L[lt * 16 + r];
#pragma unroll
        for (int reg = 0; reg < 4; ++reg)
            outB[(long)(q * 4 + reg) * 240 + lt * 16 + r] = acc[reg] + bias;
    }
}

// ---- fallback stage3: fp32 P row-major --------------------------------------
__global__ __launch_bounds__(256) void stage3_fb(const float* __restrict__ P,
                                                 const float* __restrict__ b1,
                                                 const float* __restrict__ W2,
                                                 const float* __restrict__ b2,
                                                 float* __restrict__ out) {
    __shared__ float h2[32][36];
    const int tid = threadIdx.x;
    const int g0 = blockIdx.x * 32;
    const int b  = g0 >> 12;
    const int n0 = g0 & 4095;
    {
        const int rr = tid >> 3, cg = tid & 7;
        const float* base = P + (long)(n0 + rr) * C_ + b * 32 + cg * 4;
        f32x4 v = *(const f32x4*)base;
        f32x4 bb = *(const f32x4*)(b1 + cg * 4);
#pragma unroll
        for (int e = 0; e < 4; ++e) {
            float s = v[e] + bb[e];
            h2[rr][cg * 4 + e] = s > 0.f ? s : 0.f;
        }
    }
    __syncthreads();
    if (tid < 240) {
        const int l = tid;
        float w2r[32];
#pragma unroll
        for (int h = 0; h < 32; ++h) w2r[h] = W2[h * 240 + l];
        const float bias = b2[l];
        for (int rr = 0; rr < 32; ++rr) {
            const f32x4* hv = (const f32x4*)h2[rr];
            float acc = bias;
#pragma unroll
            for (int hh = 0; hh < 8; ++hh) {
                f32x4 v = hv[hh];
                acc += v[0] * w2r[hh*4+0]; acc += v[1] * w2r[hh*4+1];
                acc += v[2] * w2r[hh*4+2]; acc += v[3] * w2r[hh*4+3];
            }
            out[(long)(g0 + rr) * 240 + l] = acc;
        }
    }
}

extern "C" void kernel_launch(void* const* d_in, const int* in_sizes, int n_in,
                              void* d_out, int out_size, void* d_ws, size_t ws_size,
                              hipStream_t stream) {
    const float* x  = (const float*)d_in[0];
    const float* a  = (const float*)d_in[1];
    const float* W1 = (const float*)d_in[2];
    const float* b1 = (const float*)d_in[3];
    const float* W2 = (const float*)d_in[4];
    const float* b2 = (const float*)d_in[5];
    float* out = (float*)d_out;

    short* HcF = (short*)d_ws;                                 // 2 MB bf16 frag-order
    void*  P   = (void*)((char*)d_ws + (size_t)C_ * N_ * 2);
    const size_t need_main = (size_t)C_ * N_ * 2 + (size_t)KS * N_ * C_ * 2;
    const size_t need_fb   = (size_t)C_ * N_ * 2 + (size_t)N_ * C_ * 4;

    stage1<<<512, 256, 0, stream>>>(x, W1, HcF);
    if (ws_size >= need_main) {
        stage2<<<512, 256, 0, stream>>>(a, HcF, (short*)P);
        stage3<<<256, 512, 0, stream>>>((const short*)P, b1, W2, b2, out);
    } else if (ws_size >= need_fb) {
        hipMemsetAsync(P, 0, (size_t)N_ * C_ * 4, stream);
        stage2_fb<<<512, 256, 0, stream>>>(a, HcF, (float*)P);
        stage3_fb<<<1024, 256, 0, stream>>>((const float*)P, b1, W2, b2, out);
    }
}